// Round 8
// baseline (311.889 us; speedup 1.0000x reference)
//
#include <hip/hip_runtime.h>
#include <stdint.h>

#define AS1 __attribute__((address_space(1)))
#define AS3 __attribute__((address_space(3)))

typedef short short8 __attribute__((ext_vector_type(8)));
typedef unsigned short ushort8 __attribute__((ext_vector_type(8)));
typedef __bf16 bf16x8 __attribute__((ext_vector_type(8)));
typedef float floatx4 __attribute__((ext_vector_type(4)));

__device__ __forceinline__ floatx4 mfma16(short8 a, short8 b, floatx4 c) {
  return __builtin_amdgcn_mfma_f32_16x16x32_bf16(
      __builtin_bit_cast(bf16x8, a), __builtin_bit_cast(bf16x8, b), c, 0, 0, 0);
}

__device__ __forceinline__ unsigned short f2bf(float f) {
  uint32_t u = __builtin_bit_cast(uint32_t, f);
  u = (u + 0x7FFFu + ((u >> 16) & 1u)) >> 16;
  return (unsigned short)u;
}

// packed f32x2 -> bf16x2 (RTNE), 1 VALU instr
__device__ __forceinline__ uint32_t cvt_pk_bf16(float a, float b) {
  uint32_t d;
  asm("v_cvt_pk_bf16_f32 %0, %1, %2" : "=v"(d) : "v"(a), "v"(b));
  return d;
}

// ---------------------------------------------------------------------------
// Convert W only: Wq|Wk|Wv -> Wqkv (3072x1024 bf16), Wo -> bf16. x is now
// consumed in f32 directly by gemm_qkv. 2^20 float4 groups.
// ---------------------------------------------------------------------------
__global__ __launch_bounds__(256) void convert_w(
    const float4* __restrict__ wq, const float4* __restrict__ wk,
    const float4* __restrict__ wv, const float4* __restrict__ wo,
    ushort4* __restrict__ wqkvb, ushort4* __restrict__ wob) {
  int i = blockIdx.x * 256 + threadIdx.x;
  int r = i >> 18;  // 0..3 -> Wq,Wk,Wv,Wo (2^18 float4 each)
  int j = i & ((1 << 18) - 1);
  const float4* src = (r == 0 ? wq : r == 1 ? wk : r == 2 ? wv : wo) + j;
  ushort4* dst = (r < 3) ? (wqkvb + (r << 18) + j) : (wob + j);
  float4 v = *src;
  ushort4 o;
  o.x = f2bf(v.x);
  o.y = f2bf(v.y);
  o.z = f2bf(v.z);
  o.w = f2bf(v.w);
  *dst = o;
}

// ---------------------------------------------------------------------------
// QKV GEMM, 128x128 tile: C = x @ Wqkv^T, A read DIRECTLY in f32 (fused
// convert). LDS: A f32 32 KB (16 subtiles of 16 rows x 32 k, with per-row
// 16B-unit swizzle (u + row) & 7 -> same conflict-free modular pattern as the
// proven bf16 path) + B bf16 16 KB = 48 KB -> 3 WG/CU. A frags are built with
// 2x ds_read_b128 + 4x v_cvt_pk_bf16_f32 (RTNE, numerics identical to the
// old pre-converted path).
// ---------------------------------------------------------------------------
__global__ __launch_bounds__(256) void gemm_qkv(const float* __restrict__ A,
                                                const unsigned short* __restrict__ Bm,
                                                unsigned short* __restrict__ C) {
  const int N = 3072, K = 1024;
  __shared__ __align__(16) unsigned char lds[49152];  // A: 0..32K, B: 32K..48K
  unsigned short* ldsB = (unsigned short*)(lds + 32768);
  const int tid = threadIdx.x;
  const int lane = tid & 63;
  const int w = tid >> 6;
  const int wr = w >> 1, wc = w & 1;
  const int tm = blockIdx.x * 128, tn = blockIdx.y * 128;
  const int lrow = lane & 15;
  const int lkg = lane >> 4;
  // A staging lane geometry (per chunk): 8 rows x 8 units of 16B
  const int srow = lane >> 3;  // row within chunk 0..7
  const int sL = lane & 7;     // LDS 16B unit 0..7

  floatx4 acc[4][4];
#pragma unroll
  for (int i = 0; i < 4; ++i)
#pragma unroll
    for (int j = 0; j < 4; ++j) acc[i][j] = floatx4{0.f, 0.f, 0.f, 0.f};

  for (int k0 = 0; k0 < K; k0 += 64) {
    // 48 chunks of 1KB: A chunks 0..31 (c = mt*4 + ks*2 + h), B chunks 32..47
#pragma unroll
    for (int c = w * 12; c < w * 12 + 12; ++c) {
      if (c < 32) {
        int mt = c >> 2, ks = (c >> 1) & 1, h = c & 1;
        int rin = h * 8 + srow;            // row within subtile 0..15
        int gu = (sL - rin) & 7;           // swizzled global 16B unit
        const float* g = A + (size_t)(tm + mt * 16 + rin) * K + k0 + ks * 32 + gu * 4;
        __builtin_amdgcn_global_load_lds((const AS1 uint32_t*)g,
                                         (AS3 uint32_t*)(lds + c * 1024), 16, 0, 0);
      } else {
        int b = c - 32;
        int nt = b >> 1, ks = b & 1;
        const unsigned short* g =
            Bm + (size_t)(tn + nt * 16 + lrow) * K + (k0 + ks * 32 + lkg * 8);
        __builtin_amdgcn_global_load_lds((const AS1 uint32_t*)g,
                                         (AS3 uint32_t*)(lds + 32768 + b * 1024), 16, 0, 0);
      }
    }
    __syncthreads();
#pragma unroll
    for (int ks = 0; ks < 2; ++ks) {
      short8 af[4], bf[4];
#pragma unroll
      for (int i = 0; i < 4; ++i) {
        int mt = wr * 4 + i;
        const unsigned char* sb = lds + (mt * 2 + ks) * 2048 + lrow * 128;
        float4 x0 = *(const float4*)(sb + ((2 * lkg + lrow) & 7) * 16);
        float4 x1 = *(const float4*)(sb + ((2 * lkg + 1 + lrow) & 7) * 16);
        uint4 pk;
        pk.x = cvt_pk_bf16(x0.x, x0.y);
        pk.y = cvt_pk_bf16(x0.z, x0.w);
        pk.z = cvt_pk_bf16(x1.x, x1.y);
        pk.w = cvt_pk_bf16(x1.z, x1.w);
        af[i] = __builtin_bit_cast(short8, pk);
      }
#pragma unroll
      for (int j = 0; j < 4; ++j)
        bf[j] = *(const short8*)&ldsB[((wc * 4 + j) * 2 + ks) * 512 + lane * 8];
#pragma unroll
      for (int i = 0; i < 4; ++i)
#pragma unroll
        for (int j = 0; j < 4; ++j) acc[i][j] = mfma16(af[i], bf[j], acc[i][j]);
    }
    __syncthreads();
  }
  const int r0 = (lane >> 4) * 4;
#pragma unroll
  for (int i = 0; i < 4; ++i)
#pragma unroll
    for (int j = 0; j < 4; ++j)
#pragma unroll
      for (int r = 0; r < 4; ++r) {
        int row = tm + wr * 64 + i * 16 + r0 + r;
        int col = tn + wc * 64 + j * 16 + lrow;
        C[(size_t)row * N + col] = f2bf(acc[i][j][r]);
      }
}

// ---------------------------------------------------------------------------
// GEMM 64x128 tile (output projection; 512 WGs at N=1024 -> 2/CU).
// ---------------------------------------------------------------------------
__global__ __launch_bounds__(256) void gemm64(const unsigned short* __restrict__ A,
                                              const unsigned short* __restrict__ Bm,
                                              float* __restrict__ C, int N, int K) {
  __shared__ unsigned short lds[24 * 512];  // A: 0-7, B: 8-23
  const int tid = threadIdx.x;
  const int lane = tid & 63;
  const int w = tid >> 6;
  const int wr = w >> 1, wc = w & 1;
  const int tm = blockIdx.x * 64, tn = blockIdx.y * 128;
  const int lrow = lane & 15;
  const int lk = (lane >> 4) * 8;

  floatx4 acc[2][4];
#pragma unroll
  for (int i = 0; i < 2; ++i)
#pragma unroll
    for (int j = 0; j < 4; ++j) acc[i][j] = floatx4{0.f, 0.f, 0.f, 0.f};

  for (int k0 = 0; k0 < K; k0 += 64) {
#pragma unroll
    for (int c = w * 6; c < w * 6 + 6; ++c) {
      const unsigned short* g;
      if (c < 8) {
        int mt = c >> 1, ks = c & 1;
        g = A + (size_t)(tm + mt * 16 + lrow) * K + (k0 + ks * 32 + lk);
      } else {
        int cc = c - 8;
        int nt = cc >> 1, ks = cc & 1;
        g = Bm + (size_t)(tn + nt * 16 + lrow) * K + (k0 + ks * 32 + lk);
      }
      __builtin_amdgcn_global_load_lds((const AS1 uint32_t*)g,
                                       (AS3 uint32_t*)(&lds[c * 512]), 16, 0, 0);
    }
    __syncthreads();
#pragma unroll
    for (int ks = 0; ks < 2; ++ks) {
      short8 af[2], bf[4];
#pragma unroll
      for (int i = 0; i < 2; ++i)
        af[i] = *(const short8*)&lds[((wr * 2 + i) * 2 + ks) * 512 + lane * 8];
#pragma unroll
      for (int j = 0; j < 4; ++j)
        bf[j] = *(const short8*)&lds[(8 + (wc * 4 + j) * 2 + ks) * 512 + lane * 8];
#pragma unroll
      for (int i = 0; i < 2; ++i)
#pragma unroll
        for (int j = 0; j < 4; ++j) acc[i][j] = mfma16(af[i], bf[j], acc[i][j]);
    }
    __syncthreads();
  }
  const int r0 = (lane >> 4) * 4;
#pragma unroll
  for (int i = 0; i < 2; ++i)
#pragma unroll
    for (int j = 0; j < 4; ++j)
#pragma unroll
      for (int r = 0; r < 4; ++r) {
        int row = tm + (wr * 2 + i) * 16 + r0 + r;
        int col = tn + (wc * 4 + j) * 16 + lrow;
        C[(size_t)row * N + col] = acc[i][j][r];
      }
}

// ---------------------------------------------------------------------------
// Flash attention, fixed-offset softmax + wave-uniform masked-tile skipping.
// ctv = # tiles with any causally-visible key; ctl = # tiles fully below the
// window. Interior blocks (ctl==0, ctv==8) take the unrolled fast path;
// boundary blocks compute only [ctl, ctv) and zero PT for the kk-aligned rest.
// ---------------------------------------------------------------------------
__global__ __launch_bounds__(256) void attn_kernel(const unsigned short* __restrict__ qkv,
                                                   unsigned short* __restrict__ aout) {
  __shared__ unsigned short Klds[2][16 * 512];  // 2 x 16KB A-frag chunks
  __shared__ unsigned short VT[64 * 136];       // V^T [d][key], stride 136
  __shared__ unsigned short PT[4][16 * 136];    // per-wave P^T [q][key]

  const int tid = threadIdx.x;
  const int lane = tid & 63;
  const int w = tid >> 6;
  const int lrow = lane & 15;
  const int lkg = lane >> 4;

  const int i = blockIdx.x;
  const int half = i >> 8;
  const int j = (i >> 3) & 31;
  const int h = 2 * (i & 7) + half;
  const int qb = half ? (31 - j) : j;
  const int q0 = qb * 128;

  short8 qf[2][2];
#pragma unroll
  for (int qt = 0; qt < 2; ++qt)
#pragma unroll
    for (int ks = 0; ks < 2; ++ks)
      qf[qt][ks] = *(const short8*)&qkv[(size_t)(q0 + qt * 64 + w * 16 + lrow) * 3072 +
                                        h * 64 + ks * 32 + lkg * 8];

  float l_i[2] = {0.f, 0.f};
  floatx4 o[4][2];
#pragma unroll
  for (int qt = 0; qt < 2; ++qt)
#pragma unroll
    for (int nt = 0; nt < 4; ++nt) o[nt][qt] = floatx4{0.f, 0.f, 0.f, 0.f};

  const float scale2 = 0.125f * 1.44269504088896f;  // 1/sqrt(64) * log2(e)
  const float OFF = 16.0f;                          // fixed softmax offset (log2)

  // ---- prologue: stage sink K/V; prefetch window block 0 ----
  if (w < 2) {
    const unsigned short* g = &qkv[(size_t)lrow * 3072 + 1024 + h * 64 + w * 32 + lkg * 8];
    __builtin_amdgcn_global_load_lds((const AS1 uint32_t*)g,
                                     (AS3 uint32_t*)(&Klds[0][w * 512]), 16, 0, 0);
  }
  {
    if (lane < 16) {
      const unsigned short* g0 = &qkv[(size_t)(2 * lane) * 3072 + 2048 + h * 64 + w * 16];
      ushort8 a0 = *(const ushort8*)g0;
      ushort8 a1 = *(const ushort8*)(g0 + 8);
      ushort8 b0 = *(const ushort8*)(g0 + 3072);
      ushort8 b1 = *(const ushort8*)(g0 + 3080);
      uint32_t* vt = (uint32_t*)VT;
#pragma unroll
      for (int dd = 0; dd < 8; ++dd) {
        vt[(w * 16 + dd) * 68 + lane] = (uint32_t)a0[dd] | ((uint32_t)b0[dd] << 16);
        vt[(w * 16 + 8 + dd) * 68 + lane] = (uint32_t)a1[dd] | ((uint32_t)b1[dd] << 16);
      }
    }
  }
  const int kb0 = (q0 - 511 < 16) ? 16 : (q0 - 511);
#pragma unroll
  for (int c = 0; c < 4; ++c) {
    int ch = w * 4 + c;
    int kt = ch >> 1, ks = ch & 1;
    const unsigned short* g =
        &qkv[(size_t)(kb0 + kt * 16 + lrow) * 3072 + 1024 + h * 64 + ks * 32 + lkg * 8];
    __builtin_amdgcn_global_load_lds((const AS1 uint32_t*)g,
                                     (AS3 uint32_t*)(&Klds[1][ch * 512]), 16, 0, 0);
  }
  ushort8 va0, va1, vb0, vb1;
  {
    const unsigned short* g0 = &qkv[(size_t)(kb0 + 2 * lane) * 3072 + 2048 + h * 64 + w * 16];
    va0 = *(const ushort8*)g0;
    va1 = *(const ushort8*)(g0 + 8);
    vb0 = *(const ushort8*)(g0 + 3072);
    vb1 = *(const ushort8*)(g0 + 3080);
  }
  __syncthreads();

  // ---- sink compute (keys 0..15; PV over 0..31 with P=0 padding) ----
#pragma unroll
  for (int qt = 0; qt < 2; ++qt) {
    const int qq = q0 + qt * 64 + w * 16 + lrow;
    floatx4 s0 = floatx4{0.f, 0.f, 0.f, 0.f};
#pragma unroll
    for (int ks = 0; ks < 2; ++ks) {
      short8 kf = *(const short8*)&Klds[0][ks * 512 + lane * 8];
      s0 = mfma16(kf, qf[qt][ks], s0);
    }
    float p[4];
#pragma unroll
    for (int r = 0; r < 4; ++r) {
      int key = lkg * 4 + r;
      bool vis = (key <= qq) && ((key < 4) || (key >= qq - 511));
      float sv = vis ? fmaf(s0[r], scale2, -OFF) : -1e30f;
      p[r] = exp2f(sv);
    }
    l_i[qt] += (p[0] + p[1]) + (p[2] + p[3]);
    *(uint2*)&PT[w][lrow * 136 + lkg * 4] =
        uint2{cvt_pk_bf16(p[0], p[1]), cvt_pk_bf16(p[2], p[3])};
    *(uint2*)&PT[w][lrow * 136 + 16 + lkg * 4] = uint2{0u, 0u};
    short8 pf = *(const short8*)&PT[w][lrow * 136 + lkg * 8];
#pragma unroll
    for (int nt = 0; nt < 4; ++nt) {
      short8 vf = *(const short8*)&VT[(nt * 16 + lrow) * 136 + lkg * 8];
      o[nt][qt] = mfma16(vf, pf, o[nt][qt]);
    }
  }

  // ---- window blocks of 128 keys (pipelined) ----
  int nbuf = 1;
  for (int kb = kb0; kb < q0 + 128; kb += 128) {
    const bool hasnext = (kb + 128 < q0 + 128);
    __syncthreads();
    {
      uint32_t* vt = (uint32_t*)VT;
#pragma unroll
      for (int dd = 0; dd < 8; ++dd) {
        vt[(w * 16 + dd) * 68 + lane] = (uint32_t)va0[dd] | ((uint32_t)vb0[dd] << 16);
        vt[(w * 16 + 8 + dd) * 68 + lane] = (uint32_t)va1[dd] | ((uint32_t)vb1[dd] << 16);
      }
    }
    __syncthreads();

    if (hasnext) {
      const int kn = kb + 128;
#pragma unroll
      for (int c = 0; c < 4; ++c) {
        int ch = w * 4 + c;
        int kt = ch >> 1, ks = ch & 1;
        const unsigned short* g =
            &qkv[(size_t)(kn + kt * 16 + lrow) * 3072 + 1024 + h * 64 + ks * 32 + lkg * 8];
        __builtin_amdgcn_global_load_lds((const AS1 uint32_t*)g,
                                         (AS3 uint32_t*)(&Klds[1 - nbuf][ch * 512]), 16, 0, 0);
      }
      const unsigned short* g0 = &qkv[(size_t)(kn + 2 * lane) * 3072 + 2048 + h * 64 + w * 16];
      va0 = *(const ushort8*)g0;
      va1 = *(const ushort8*)(g0 + 8);
      vb0 = *(const ushort8*)(g0 + 3072);
      vb1 = *(const ushort8*)(g0 + 3080);
    }

#pragma unroll
    for (int qt = 0; qt < 2; ++qt) {
      const int qaT = q0 + qt * 64 + w * 16;  // wave-uniform
      const int qq = qaT + lrow;
      // tile bounds (wave-uniform): [ctl, ctv) have visible keys
      int ctv = (qaT + 31 - kb) >> 4;
      ctv = ctv < 0 ? 0 : (ctv > 8 ? 8 : ctv);
      int ctl = (qaT - 511 - kb) >> 4;
      ctl = ctl < 0 ? 0 : (ctl > ctv ? ctv : ctl);

      if (ctl == 0 && ctv == 8) {
        // ---- fast path: all 8 tiles active ----
        floatx4 s[8];
#pragma unroll
        for (int ct = 0; ct < 8; ++ct) {
          s[ct] = floatx4{0.f, 0.f, 0.f, 0.f};
#pragma unroll
          for (int ks = 0; ks < 2; ++ks) {
            short8 kf = *(const short8*)&Klds[nbuf][(ct * 2 + ks) * 512 + lane * 8];
            s[ct] = mfma16(kf, qf[qt][ks], s[ct]);
          }
        }
        const bool full = (kb + 127 <= qaT) && (kb >= qaT + 15 - 511);
        float ps = 0.f;
#pragma unroll
        for (int ct = 0; ct < 8; ++ct) {
          float p[4];
#pragma unroll
          for (int r = 0; r < 4; ++r) {
            float sv = fmaf(s[ct][r], scale2, -OFF);
            if (!full) {
              int key = kb + ct * 16 + lkg * 4 + r;
              bool vis = (key <= qq) && (key >= qq - 511);
              sv = vis ? sv : -1e30f;
            }
            p[r] = exp2f(sv);
          }
          ps += (p[0] + p[1]) + (p[2] + p[3]);
          *(uint2*)&PT[w][lrow * 136 + ct * 16 + lkg * 4] =
              uint2{cvt_pk_bf16(p[0], p[1]), cvt_pk_bf16(p[2], p[3])};
        }
        l_i[qt] += ps;
#pragma unroll
        for (int kk = 0; kk < 4; ++kk) {
          short8 pf = *(const short8*)&PT[w][lrow * 136 + kk * 32 + lkg * 8];
#pragma unroll
          for (int nt = 0; nt < 4; ++nt) {
            short8 vf = *(const short8*)&VT[(nt * 16 + lrow) * 136 + kk * 32 + lkg * 8];
            o[nt][qt] = mfma16(vf, pf, o[nt][qt]);
          }
        }
      } else if (ctv > ctl) {
        // ---- boundary path: compute [ctl, ctv), zero kk-aligned rest ----
        const int kk_lo = ctl >> 1;
        const int kk_hi = (ctv + 1) >> 1;
        floatx4 s[8];
        for (int ct = ctl; ct < ctv; ++ct) {
          s[ct] = floatx4{0.f, 0.f, 0.f, 0.f};
#pragma unroll
          for (int ks = 0; ks < 2; ++ks) {
            short8 kf = *(const short8*)&Klds[nbuf][(ct * 2 + ks) * 512 + lane * 8];
            s[ct] = mfma16(kf, qf[qt][ks], s[ct]);
          }
        }
        float ps = 0.f;
        for (int ct = 2 * kk_lo; ct < 2 * kk_hi; ++ct) {
          if (ct >= ctl && ct < ctv) {
            float p[4];
#pragma unroll
            for (int r = 0; r < 4; ++r) {
              int key = kb + ct * 16 + lkg * 4 + r;
              bool vis = (key <= qq) && (key >= qq - 511);
              float sv = vis ? fmaf(s[ct][r], scale2, -OFF) : -1e30f;
              p[r] = exp2f(sv);
            }
            ps += (p[0] + p[1]) + (p[2] + p[3]);
            *(uint2*)&PT[w][lrow * 136 + ct * 16 + lkg * 4] =
                uint2{cvt_pk_bf16(p[0], p[1]), cvt_pk_bf16(p[2], p[3])};
          } else {
            *(uint2*)&PT[w][lrow * 136 + ct * 16 + lkg * 4] = uint2{0u, 0u};
          }
        }
        l_i[qt] += ps;
        for (int kk = kk_lo; kk < kk_hi; ++kk) {
          short8 pf = *(const short8*)&PT[w][lrow * 136 + kk * 32 + lkg * 8];
#pragma unroll
          for (int nt = 0; nt < 4; ++nt) {
            short8 vf = *(const short8*)&VT[(nt * 16 + lrow) * 136 + kk * 32 + lkg * 8];
            o[nt][qt] = mfma16(vf, pf, o[nt][qt]);
          }
        }
      }
    }
    nbuf ^= 1;
  }

  // single final l reduction across the 4 key-stripes (lanes share lrow=q)
#pragma unroll
  for (int qt = 0; qt < 2; ++qt) {
    float l = l_i[qt];
    l += __shfl_xor(l, 16);
    l += __shfl_xor(l, 32);
    const float inv = 1.0f / l;
    const int qq = q0 + qt * 64 + w * 16 + lrow;
#pragma unroll
    for (int nt = 0; nt < 4; ++nt) {
      floatx4 ov = o[nt][qt];
      uint32_t lo = cvt_pk_bf16(ov[0] * inv, ov[1] * inv);
      uint32_t hi = cvt_pk_bf16(ov[2] * inv, ov[3] * inv);
      *(uint2*)&aout[(size_t)qq * 1024 + h * 64 + nt * 16 + lkg * 4] = uint2{lo, hi};
    }
  }
}

// ---------------------------------------------------------------------------
extern "C" void kernel_launch(void* const* d_in, const int* in_sizes, int n_in,
                              void* d_out, int out_size, void* d_ws, size_t ws_size,
                              hipStream_t stream) {
  const float* x = (const float*)d_in[0];
  const float* wq = (const float*)d_in[1];
  const float* wk = (const float*)d_in[2];
  const float* wv = (const float*)d_in[3];
  const float* wo = (const float*)d_in[4];

  char* ws = (char*)d_ws;
  unsigned short* Wqkv = (unsigned short*)(ws + (8u << 20));  // 6 MB
  unsigned short* Wob = (unsigned short*)(ws + (14u << 20));  // 2 MB
  unsigned short* QKV = (unsigned short*)(ws + (16u << 20));  // 24 MB
  unsigned short* AO = (unsigned short*)(ws + (40u << 20));   // 8 MB

  convert_w<<<4096, 256, 0, stream>>>((const float4*)wq, (const float4*)wk,
                                      (const float4*)wv, (const float4*)wo,
                                      (ushort4*)Wqkv, (ushort4*)Wob);
  gemm_qkv<<<dim3(32, 24), 256, 0, stream>>>(x, Wqkv, QKV);
  attn_kernel<<<512, 256, 0, stream>>>(QKV, AO);
  gemm64<<<dim3(64, 8), 256, 0, stream>>>(AO, Wob, (float*)d_out, 1024, 1024);
}

// Round 9
// 212.765 us; speedup vs baseline: 1.4659x; 1.4659x over previous
//
#include <hip/hip_runtime.h>
#include <stdint.h>

#define AS1 __attribute__((address_space(1)))
#define AS3 __attribute__((address_space(3)))

typedef short short8 __attribute__((ext_vector_type(8)));
typedef unsigned short ushort8 __attribute__((ext_vector_type(8)));
typedef __bf16 bf16x8 __attribute__((ext_vector_type(8)));
typedef float floatx4 __attribute__((ext_vector_type(4)));

__device__ __forceinline__ floatx4 mfma16(short8 a, short8 b, floatx4 c) {
  return __builtin_amdgcn_mfma_f32_16x16x32_bf16(
      __builtin_bit_cast(bf16x8, a), __builtin_bit_cast(bf16x8, b), c, 0, 0, 0);
}

__device__ __forceinline__ unsigned short f2bf(float f) {
  uint32_t u = __builtin_bit_cast(uint32_t, f);
  u = (u + 0x7FFFu + ((u >> 16) & 1u)) >> 16;
  return (unsigned short)u;
}

// packed f32x2 -> bf16x2 (RTNE), 1 VALU instr
__device__ __forceinline__ uint32_t cvt_pk_bf16(float a, float b) {
  uint32_t d;
  asm("v_cvt_pk_bf16_f32 %0, %1, %2" : "=v"(d) : "v"(a), "v"(b));
  return d;
}

// ---------------------------------------------------------------------------
// Convert W only: Wq|Wk|Wv -> Wqkv (3072x1024 bf16), Wo -> bf16. x is
// consumed in f32 directly by gemm_qkv. 2^20 float4 groups.
// ---------------------------------------------------------------------------
__global__ __launch_bounds__(256) void convert_w(
    const float4* __restrict__ wq, const float4* __restrict__ wk,
    const float4* __restrict__ wv, const float4* __restrict__ wo,
    ushort4* __restrict__ wqkvb, ushort4* __restrict__ wob) {
  int i = blockIdx.x * 256 + threadIdx.x;
  int r = i >> 18;  // 0..3 -> Wq,Wk,Wv,Wo (2^18 float4 each)
  int j = i & ((1 << 18) - 1);
  const float4* src = (r == 0 ? wq : r == 1 ? wk : r == 2 ? wv : wo) + j;
  ushort4* dst = (r < 3) ? (wqkvb + (r << 18) + j) : (wob + j);
  float4 v = *src;
  ushort4 o;
  o.x = f2bf(v.x);
  o.y = f2bf(v.y);
  o.z = f2bf(v.z);
  o.w = f2bf(v.w);
  *dst = o;
}

// ---------------------------------------------------------------------------
// QKV GEMM, 128x128 tile: C = x @ Wqkv^T, A read DIRECTLY in f32 (fused
// convert). LDS: A f32 32 KB (swizzled 16B units) + B bf16 16 KB = 48 KB.
// A frags: 2x ds_read_b128 + 4x v_cvt_pk_bf16_f32 (RTNE == old pre-convert).
// ---------------------------------------------------------------------------
__global__ __launch_bounds__(256) void gemm_qkv(const float* __restrict__ A,
                                                const unsigned short* __restrict__ Bm,
                                                unsigned short* __restrict__ C) {
  const int N = 3072, K = 1024;
  __shared__ __align__(16) unsigned char lds[49152];  // A: 0..32K, B: 32K..48K
  unsigned short* ldsB = (unsigned short*)(lds + 32768);
  const int tid = threadIdx.x;
  const int lane = tid & 63;
  const int w = tid >> 6;
  const int wr = w >> 1, wc = w & 1;
  const int tm = blockIdx.x * 128, tn = blockIdx.y * 128;
  const int lrow = lane & 15;
  const int lkg = lane >> 4;
  const int srow = lane >> 3;  // staging row within chunk 0..7
  const int sL = lane & 7;     // staging LDS 16B unit 0..7

  floatx4 acc[4][4];
#pragma unroll
  for (int i = 0; i < 4; ++i)
#pragma unroll
    for (int j = 0; j < 4; ++j) acc[i][j] = floatx4{0.f, 0.f, 0.f, 0.f};

  for (int k0 = 0; k0 < K; k0 += 64) {
    // 48 chunks of 1KB: A chunks 0..31 (c = mt*4 + ks*2 + h), B chunks 32..47
#pragma unroll
    for (int c = w * 12; c < w * 12 + 12; ++c) {
      if (c < 32) {
        int mt = c >> 2, ks = (c >> 1) & 1, h = c & 1;
        int rin = h * 8 + srow;   // row within subtile 0..15
        int gu = (sL - rin) & 7;  // swizzled global 16B unit
        const float* g = A + (size_t)(tm + mt * 16 + rin) * K + k0 + ks * 32 + gu * 4;
        __builtin_amdgcn_global_load_lds((const AS1 uint32_t*)g,
                                         (AS3 uint32_t*)(lds + c * 1024), 16, 0, 0);
      } else {
        int b = c - 32;
        int nt = b >> 1, ks = b & 1;
        const unsigned short* g =
            Bm + (size_t)(tn + nt * 16 + lrow) * K + (k0 + ks * 32 + lkg * 8);
        __builtin_amdgcn_global_load_lds((const AS1 uint32_t*)g,
                                         (AS3 uint32_t*)(lds + 32768 + b * 1024), 16, 0, 0);
      }
    }
    __syncthreads();
#pragma unroll
    for (int ks = 0; ks < 2; ++ks) {
      short8 af[4], bf[4];
#pragma unroll
      for (int i = 0; i < 4; ++i) {
        int mt = wr * 4 + i;
        const unsigned char* sb = lds + (mt * 2 + ks) * 2048 + lrow * 128;
        float4 x0 = *(const float4*)(sb + ((2 * lkg + lrow) & 7) * 16);
        float4 x1 = *(const float4*)(sb + ((2 * lkg + 1 + lrow) & 7) * 16);
        uint4 pk;
        pk.x = cvt_pk_bf16(x0.x, x0.y);
        pk.y = cvt_pk_bf16(x0.z, x0.w);
        pk.z = cvt_pk_bf16(x1.x, x1.y);
        pk.w = cvt_pk_bf16(x1.z, x1.w);
        af[i] = __builtin_bit_cast(short8, pk);
      }
#pragma unroll
      for (int j = 0; j < 4; ++j)
        bf[j] = *(const short8*)&ldsB[((wc * 4 + j) * 2 + ks) * 512 + lane * 8];
#pragma unroll
      for (int i = 0; i < 4; ++i)
#pragma unroll
        for (int j = 0; j < 4; ++j) acc[i][j] = mfma16(af[i], bf[j], acc[i][j]);
    }
    __syncthreads();
  }
  const int r0 = (lane >> 4) * 4;
#pragma unroll
  for (int i = 0; i < 4; ++i)
#pragma unroll
    for (int j = 0; j < 4; ++j)
#pragma unroll
      for (int r = 0; r < 4; ++r) {
        int row = tm + wr * 64 + i * 16 + r0 + r;
        int col = tn + wc * 64 + j * 16 + lrow;
        C[(size_t)row * N + col] = f2bf(acc[i][j][r]);
      }
}

// ---------------------------------------------------------------------------
// GEMM 64x128 tile (output projection; 512 WGs at N=1024 -> 2/CU).
// ---------------------------------------------------------------------------
__global__ __launch_bounds__(256) void gemm64(const unsigned short* __restrict__ A,
                                              const unsigned short* __restrict__ Bm,
                                              float* __restrict__ C, int N, int K) {
  __shared__ unsigned short lds[24 * 512];  // A: 0-7, B: 8-23
  const int tid = threadIdx.x;
  const int lane = tid & 63;
  const int w = tid >> 6;
  const int wr = w >> 1, wc = w & 1;
  const int tm = blockIdx.x * 64, tn = blockIdx.y * 128;
  const int lrow = lane & 15;
  const int lk = (lane >> 4) * 8;

  floatx4 acc[2][4];
#pragma unroll
  for (int i = 0; i < 2; ++i)
#pragma unroll
    for (int j = 0; j < 4; ++j) acc[i][j] = floatx4{0.f, 0.f, 0.f, 0.f};

  for (int k0 = 0; k0 < K; k0 += 64) {
#pragma unroll
    for (int c = w * 6; c < w * 6 + 6; ++c) {
      const unsigned short* g;
      if (c < 8) {
        int mt = c >> 1, ks = c & 1;
        g = A + (size_t)(tm + mt * 16 + lrow) * K + (k0 + ks * 32 + lk);
      } else {
        int cc = c - 8;
        int nt = cc >> 1, ks = cc & 1;
        g = Bm + (size_t)(tn + nt * 16 + lrow) * K + (k0 + ks * 32 + lk);
      }
      __builtin_amdgcn_global_load_lds((const AS1 uint32_t*)g,
                                       (AS3 uint32_t*)(&lds[c * 512]), 16, 0, 0);
    }
    __syncthreads();
#pragma unroll
    for (int ks = 0; ks < 2; ++ks) {
      short8 af[2], bf[4];
#pragma unroll
      for (int i = 0; i < 2; ++i)
        af[i] = *(const short8*)&lds[((wr * 2 + i) * 2 + ks) * 512 + lane * 8];
#pragma unroll
      for (int j = 0; j < 4; ++j)
        bf[j] = *(const short8*)&lds[(8 + (wc * 4 + j) * 2 + ks) * 512 + lane * 8];
#pragma unroll
      for (int i = 0; i < 2; ++i)
#pragma unroll
        for (int j = 0; j < 4; ++j) acc[i][j] = mfma16(af[i], bf[j], acc[i][j]);
    }
    __syncthreads();
  }
  const int r0 = (lane >> 4) * 4;
#pragma unroll
  for (int i = 0; i < 2; ++i)
#pragma unroll
    for (int j = 0; j < 4; ++j)
#pragma unroll
      for (int r = 0; r < 4; ++r) {
        int row = tm + (wr * 2 + i) * 16 + r0 + r;
        int col = tn + (wc * 4 + j) * 16 + lrow;
        C[(size_t)row * N + col] = acc[i][j][r];
      }
}

// ---------------------------------------------------------------------------
// Flash attention (R7 known-good): fixed-offset softmax, fully unrolled
// (NO dynamic-bound tile skipping — R8 showed it forces s[] to scratch:
// VGPR 72->120, 4x slowdown). S^T orientation, 128 q/WG, 128-key blocks +
// 16-key sink, XCD head mapping, K dbuf + V reg prefetch.
// ---------------------------------------------------------------------------
__global__ __launch_bounds__(256) void attn_kernel(const unsigned short* __restrict__ qkv,
                                                   unsigned short* __restrict__ aout) {
  __shared__ unsigned short Klds[2][16 * 512];  // 2 x 16KB A-frag chunks
  __shared__ unsigned short VT[64 * 136];       // V^T [d][key], stride 136
  __shared__ unsigned short PT[4][16 * 136];    // per-wave P^T [q][key]

  const int tid = threadIdx.x;
  const int lane = tid & 63;
  const int w = tid >> 6;
  const int lrow = lane & 15;
  const int lkg = lane >> 4;

  const int i = blockIdx.x;
  const int half = i >> 8;
  const int j = (i >> 3) & 31;
  const int h = 2 * (i & 7) + half;
  const int qb = half ? (31 - j) : j;
  const int q0 = qb * 128;

  short8 qf[2][2];
#pragma unroll
  for (int qt = 0; qt < 2; ++qt)
#pragma unroll
    for (int ks = 0; ks < 2; ++ks)
      qf[qt][ks] = *(const short8*)&qkv[(size_t)(q0 + qt * 64 + w * 16 + lrow) * 3072 +
                                        h * 64 + ks * 32 + lkg * 8];

  float l_i[2] = {0.f, 0.f};
  floatx4 o[4][2];
#pragma unroll
  for (int qt = 0; qt < 2; ++qt)
#pragma unroll
    for (int nt = 0; nt < 4; ++nt) o[nt][qt] = floatx4{0.f, 0.f, 0.f, 0.f};

  const float scale2 = 0.125f * 1.44269504088896f;  // 1/sqrt(64) * log2(e)
  const float OFF = 16.0f;                          // fixed softmax offset (log2)

  // ---- prologue: stage sink K/V; prefetch window block 0 ----
  if (w < 2) {
    const unsigned short* g = &qkv[(size_t)lrow * 3072 + 1024 + h * 64 + w * 32 + lkg * 8];
    __builtin_amdgcn_global_load_lds((const AS1 uint32_t*)g,
                                     (AS3 uint32_t*)(&Klds[0][w * 512]), 16, 0, 0);
  }
  {
    if (lane < 16) {
      const unsigned short* g0 = &qkv[(size_t)(2 * lane) * 3072 + 2048 + h * 64 + w * 16];
      ushort8 a0 = *(const ushort8*)g0;
      ushort8 a1 = *(const ushort8*)(g0 + 8);
      ushort8 b0 = *(const ushort8*)(g0 + 3072);
      ushort8 b1 = *(const ushort8*)(g0 + 3080);
      uint32_t* vt = (uint32_t*)VT;
#pragma unroll
      for (int dd = 0; dd < 8; ++dd) {
        vt[(w * 16 + dd) * 68 + lane] = (uint32_t)a0[dd] | ((uint32_t)b0[dd] << 16);
        vt[(w * 16 + 8 + dd) * 68 + lane] = (uint32_t)a1[dd] | ((uint32_t)b1[dd] << 16);
      }
    }
  }
  const int kb0 = (q0 - 511 < 16) ? 16 : (q0 - 511);
#pragma unroll
  for (int c = 0; c < 4; ++c) {
    int ch = w * 4 + c;
    int kt = ch >> 1, ks = ch & 1;
    const unsigned short* g =
        &qkv[(size_t)(kb0 + kt * 16 + lrow) * 3072 + 1024 + h * 64 + ks * 32 + lkg * 8];
    __builtin_amdgcn_global_load_lds((const AS1 uint32_t*)g,
                                     (AS3 uint32_t*)(&Klds[1][ch * 512]), 16, 0, 0);
  }
  ushort8 va0, va1, vb0, vb1;
  {
    const unsigned short* g0 = &qkv[(size_t)(kb0 + 2 * lane) * 3072 + 2048 + h * 64 + w * 16];
    va0 = *(const ushort8*)g0;
    va1 = *(const ushort8*)(g0 + 8);
    vb0 = *(const ushort8*)(g0 + 3072);
    vb1 = *(const ushort8*)(g0 + 3080);
  }
  __syncthreads();

  // ---- sink compute (keys 0..15; PV over 0..31 with P=0 padding) ----
#pragma unroll
  for (int qt = 0; qt < 2; ++qt) {
    const int qq = q0 + qt * 64 + w * 16 + lrow;
    floatx4 s0 = floatx4{0.f, 0.f, 0.f, 0.f};
#pragma unroll
    for (int ks = 0; ks < 2; ++ks) {
      short8 kf = *(const short8*)&Klds[0][ks * 512 + lane * 8];
      s0 = mfma16(kf, qf[qt][ks], s0);
    }
    float p[4];
#pragma unroll
    for (int r = 0; r < 4; ++r) {
      int key = lkg * 4 + r;
      bool vis = (key <= qq) && ((key < 4) || (key >= qq - 511));
      float sv = vis ? fmaf(s0[r], scale2, -OFF) : -1e30f;
      p[r] = exp2f(sv);
    }
    l_i[qt] += (p[0] + p[1]) + (p[2] + p[3]);
    *(uint2*)&PT[w][lrow * 136 + lkg * 4] =
        uint2{cvt_pk_bf16(p[0], p[1]), cvt_pk_bf16(p[2], p[3])};
    *(uint2*)&PT[w][lrow * 136 + 16 + lkg * 4] = uint2{0u, 0u};
    short8 pf = *(const short8*)&PT[w][lrow * 136 + lkg * 8];
#pragma unroll
    for (int nt = 0; nt < 4; ++nt) {
      short8 vf = *(const short8*)&VT[(nt * 16 + lrow) * 136 + lkg * 8];
      o[nt][qt] = mfma16(vf, pf, o[nt][qt]);
    }
  }

  // ---- window blocks of 128 keys (pipelined) ----
  int nbuf = 1;
  for (int kb = kb0; kb < q0 + 128; kb += 128) {
    const bool hasnext = (kb + 128 < q0 + 128);
    __syncthreads();
    {
      uint32_t* vt = (uint32_t*)VT;
#pragma unroll
      for (int dd = 0; dd < 8; ++dd) {
        vt[(w * 16 + dd) * 68 + lane] = (uint32_t)va0[dd] | ((uint32_t)vb0[dd] << 16);
        vt[(w * 16 + 8 + dd) * 68 + lane] = (uint32_t)va1[dd] | ((uint32_t)vb1[dd] << 16);
      }
    }
    __syncthreads();

    if (hasnext) {
      const int kn = kb + 128;
#pragma unroll
      for (int c = 0; c < 4; ++c) {
        int ch = w * 4 + c;
        int kt = ch >> 1, ks = ch & 1;
        const unsigned short* g =
            &qkv[(size_t)(kn + kt * 16 + lrow) * 3072 + 1024 + h * 64 + ks * 32 + lkg * 8];
        __builtin_amdgcn_global_load_lds((const AS1 uint32_t*)g,
                                         (AS3 uint32_t*)(&Klds[1 - nbuf][ch * 512]), 16, 0, 0);
      }
      const unsigned short* g0 = &qkv[(size_t)(kn + 2 * lane) * 3072 + 2048 + h * 64 + w * 16];
      va0 = *(const ushort8*)g0;
      va1 = *(const ushort8*)(g0 + 8);
      vb0 = *(const ushort8*)(g0 + 3072);
      vb1 = *(const ushort8*)(g0 + 3080);
    }

#pragma unroll
    for (int qt = 0; qt < 2; ++qt) {
      const int qaT = q0 + qt * 64 + w * 16;
      const int qq = qaT + lrow;
      floatx4 s[8];
#pragma unroll
      for (int ct = 0; ct < 8; ++ct) {
        s[ct] = floatx4{0.f, 0.f, 0.f, 0.f};
#pragma unroll
        for (int ks = 0; ks < 2; ++ks) {
          short8 kf = *(const short8*)&Klds[nbuf][(ct * 2 + ks) * 512 + lane * 8];
          s[ct] = mfma16(kf, qf[qt][ks], s[ct]);
        }
      }
      const bool full = (kb + 127 <= qaT) && (kb >= qaT + 15 - 511);
      float ps = 0.f;
#pragma unroll
      for (int ct = 0; ct < 8; ++ct) {
        float p[4];
#pragma unroll
        for (int r = 0; r < 4; ++r) {
          float sv = fmaf(s[ct][r], scale2, -OFF);
          if (!full) {
            int key = kb + ct * 16 + lkg * 4 + r;
            bool vis = (key <= qq) && (key >= qq - 511);
            sv = vis ? sv : -1e30f;
          }
          p[r] = exp2f(sv);
        }
        ps += (p[0] + p[1]) + (p[2] + p[3]);
        *(uint2*)&PT[w][lrow * 136 + ct * 16 + lkg * 4] =
            uint2{cvt_pk_bf16(p[0], p[1]), cvt_pk_bf16(p[2], p[3])};
      }
      l_i[qt] += ps;

#pragma unroll
      for (int kk = 0; kk < 4; ++kk) {
        short8 pf = *(const short8*)&PT[w][lrow * 136 + kk * 32 + lkg * 8];
#pragma unroll
        for (int nt = 0; nt < 4; ++nt) {
          short8 vf = *(const short8*)&VT[(nt * 16 + lrow) * 136 + kk * 32 + lkg * 8];
          o[nt][qt] = mfma16(vf, pf, o[nt][qt]);
        }
      }
    }
    nbuf ^= 1;
  }

  // single final l reduction across the 4 key-stripes (lanes share lrow=q)
#pragma unroll
  for (int qt = 0; qt < 2; ++qt) {
    float l = l_i[qt];
    l += __shfl_xor(l, 16);
    l += __shfl_xor(l, 32);
    const float inv = 1.0f / l;
    const int qq = q0 + qt * 64 + w * 16 + lrow;
#pragma unroll
    for (int nt = 0; nt < 4; ++nt) {
      floatx4 ov = o[nt][qt];
      uint32_t lo = cvt_pk_bf16(ov[0] * inv, ov[1] * inv);
      uint32_t hi = cvt_pk_bf16(ov[2] * inv, ov[3] * inv);
      *(uint2*)&aout[(size_t)qq * 1024 + h * 64 + nt * 16 + lkg * 4] = uint2{lo, hi};
    }
  }
}

// ---------------------------------------------------------------------------
extern "C" void kernel_launch(void* const* d_in, const int* in_sizes, int n_in,
                              void* d_out, int out_size, void* d_ws, size_t ws_size,
                              hipStream_t stream) {
  const float* x = (const float*)d_in[0];
  const float* wq = (const float*)d_in[1];
  const float* wk = (const float*)d_in[2];
  const float* wv = (const float*)d_in[3];
  const float* wo = (const float*)d_in[4];

  char* ws = (char*)d_ws;
  unsigned short* Wqkv = (unsigned short*)(ws + (8u << 20));  // 6 MB
  unsigned short* Wob = (unsigned short*)(ws + (14u << 20));  // 2 MB
  unsigned short* QKV = (unsigned short*)(ws + (16u << 20));  // 24 MB
  unsigned short* AO = (unsigned short*)(ws + (40u << 20));   // 8 MB

  convert_w<<<4096, 256, 0, stream>>>((const float4*)wq, (const float4*)wk,
                                      (const float4*)wv, (const float4*)wo,
                                      (ushort4*)Wqkv, (ushort4*)Wob);
  gemm_qkv<<<dim3(32, 24), 256, 0, stream>>>(x, Wqkv, QKV);
  attn_kernel<<<512, 256, 0, stream>>>(QKV, AO);
  gemm64<<<dim3(64, 8), 256, 0, stream>>>(AO, Wob, (float*)d_out, 1024, 1024);
}

// Round 10
// 208.764 us; speedup vs baseline: 1.4940x; 1.0192x over previous
//
#include <hip/hip_runtime.h>
#include <stdint.h>

#define AS1 __attribute__((address_space(1)))
#define AS3 __attribute__((address_space(3)))

typedef short short8 __attribute__((ext_vector_type(8)));
typedef unsigned short ushort8 __attribute__((ext_vector_type(8)));
typedef __bf16 bf16x8 __attribute__((ext_vector_type(8)));
typedef float floatx4 __attribute__((ext_vector_type(4)));

__device__ __forceinline__ floatx4 mfma16(short8 a, short8 b, floatx4 c) {
  return __builtin_amdgcn_mfma_f32_16x16x32_bf16(
      __builtin_bit_cast(bf16x8, a), __builtin_bit_cast(bf16x8, b), c, 0, 0, 0);
}

__device__ __forceinline__ unsigned short f2bf(float f) {
  uint32_t u = __builtin_bit_cast(uint32_t, f);
  u = (u + 0x7FFFu + ((u >> 16) & 1u)) >> 16;
  return (unsigned short)u;
}

// packed f32x2 -> bf16x2 (RTNE), 1 VALU instr
__device__ __forceinline__ uint32_t cvt_pk_bf16(float a, float b) {
  uint32_t d;
  asm("v_cvt_pk_bf16_f32 %0, %1, %2" : "=v"(d) : "v"(a), "v"(b));
  return d;
}

// ---------------------------------------------------------------------------
// Convert/pack: x -> bf16, Wq|Wk|Wv -> Wqkv (3072x1024 bf16), Wo -> bf16.
// (R9 measured: fusing x-convert into the GEMM is a net loss — 3.1M LDS
// conflicts + occupancy drop. Pre-convert everything.)
// ---------------------------------------------------------------------------
__global__ __launch_bounds__(256) void convert_pack(
    const float4* __restrict__ x, const float4* __restrict__ wq,
    const float4* __restrict__ wk, const float4* __restrict__ wv,
    const float4* __restrict__ wo, ushort4* __restrict__ xb,
    ushort4* __restrict__ wqkvb, ushort4* __restrict__ wob) {
  int i = blockIdx.x * 256 + threadIdx.x;
  const float4* src;
  ushort4* dst;
  if (i < (1 << 20)) {
    src = x + i;
    dst = xb + i;
  } else {
    int t = i - (1 << 20);
    int r = t >> 18;
    int j = t & ((1 << 18) - 1);
    src = (r == 0 ? wq : r == 1 ? wk : r == 2 ? wv : wo) + j;
    dst = (r < 3) ? (wqkvb + (r << 18) + j) : (wob + j);
  }
  float4 v = *src;
  ushort4 o;
  o.x = f2bf(v.x);
  o.y = f2bf(v.y);
  o.z = f2bf(v.z);
  o.w = f2bf(v.w);
  *dst = o;
}

// ---------------------------------------------------------------------------
// GEMM 128x128 tile (QKV projection): C[M][N] = A[M][K] @ B[N][K]^T.
// R5-measured best: 59.7 us, 0 LDS conflicts. No XCD swizzle (L3 holds A+B).
// ---------------------------------------------------------------------------
template <typename OutT>
__global__ __launch_bounds__(256) void gemm_bt(const unsigned short* __restrict__ A,
                                               const unsigned short* __restrict__ Bm,
                                               OutT* __restrict__ C, int N, int K) {
  __shared__ unsigned short lds[32 * 512];
  const int tid = threadIdx.x;
  const int lane = tid & 63;
  const int w = tid >> 6;
  const int wr = w >> 1, wc = w & 1;
  const int tm = blockIdx.x * 128, tn = blockIdx.y * 128;
  const int lrow = lane & 15;
  const int lk = (lane >> 4) * 8;

  floatx4 acc[4][4];
#pragma unroll
  for (int i = 0; i < 4; ++i)
#pragma unroll
    for (int j = 0; j < 4; ++j) acc[i][j] = floatx4{0.f, 0.f, 0.f, 0.f};

  for (int k0 = 0; k0 < K; k0 += 64) {
#pragma unroll
    for (int c = w; c < 32; c += 4) {
      const unsigned short* g;
      if (c < 16) {
        int mt = c >> 1, ks = c & 1;
        g = A + (size_t)(tm + mt * 16 + lrow) * K + (k0 + ks * 32 + lk);
      } else {
        int cc = c - 16;
        int nt = cc >> 1, ks = cc & 1;
        g = Bm + (size_t)(tn + nt * 16 + lrow) * K + (k0 + ks * 32 + lk);
      }
      __builtin_amdgcn_global_load_lds((const AS1 uint32_t*)g,
                                       (AS3 uint32_t*)(&lds[c * 512]), 16, 0, 0);
    }
    __syncthreads();
#pragma unroll
    for (int ks = 0; ks < 2; ++ks) {
      short8 af[4], bf[4];
#pragma unroll
      for (int i = 0; i < 4; ++i)
        af[i] = *(const short8*)&lds[((wr * 4 + i) * 2 + ks) * 512 + lane * 8];
#pragma unroll
      for (int j = 0; j < 4; ++j)
        bf[j] = *(const short8*)&lds[(16 + (wc * 4 + j) * 2 + ks) * 512 + lane * 8];
#pragma unroll
      for (int i = 0; i < 4; ++i)
#pragma unroll
        for (int j = 0; j < 4; ++j) acc[i][j] = mfma16(af[i], bf[j], acc[i][j]);
    }
    __syncthreads();
  }
  const int r0 = (lane >> 4) * 4;
#pragma unroll
  for (int i = 0; i < 4; ++i)
#pragma unroll
    for (int j = 0; j < 4; ++j)
#pragma unroll
      for (int r = 0; r < 4; ++r) {
        int row = tm + wr * 64 + i * 16 + r0 + r;
        int col = tn + wc * 64 + j * 16 + lrow;
        float v = acc[i][j][r];
        if constexpr (sizeof(OutT) == 2)
          C[(size_t)row * N + col] = f2bf(v);
        else
          C[(size_t)row * N + col] = v;
      }
}

// ---------------------------------------------------------------------------
// GEMM 64x128 tile (output projection; 512 WGs at N=1024 -> 2/CU).
// ---------------------------------------------------------------------------
__global__ __launch_bounds__(256) void gemm64(const unsigned short* __restrict__ A,
                                              const unsigned short* __restrict__ Bm,
                                              float* __restrict__ C, int N, int K) {
  __shared__ unsigned short lds[24 * 512];  // A: 0-7, B: 8-23
  const int tid = threadIdx.x;
  const int lane = tid & 63;
  const int w = tid >> 6;
  const int wr = w >> 1, wc = w & 1;
  const int tm = blockIdx.x * 64, tn = blockIdx.y * 128;
  const int lrow = lane & 15;
  const int lk = (lane >> 4) * 8;

  floatx4 acc[2][4];
#pragma unroll
  for (int i = 0; i < 2; ++i)
#pragma unroll
    for (int j = 0; j < 4; ++j) acc[i][j] = floatx4{0.f, 0.f, 0.f, 0.f};

  for (int k0 = 0; k0 < K; k0 += 64) {
#pragma unroll
    for (int c = w * 6; c < w * 6 + 6; ++c) {
      const unsigned short* g;
      if (c < 8) {
        int mt = c >> 1, ks = c & 1;
        g = A + (size_t)(tm + mt * 16 + lrow) * K + (k0 + ks * 32 + lk);
      } else {
        int cc = c - 8;
        int nt = cc >> 1, ks = cc & 1;
        g = Bm + (size_t)(tn + nt * 16 + lrow) * K + (k0 + ks * 32 + lk);
      }
      __builtin_amdgcn_global_load_lds((const AS1 uint32_t*)g,
                                       (AS3 uint32_t*)(&lds[c * 512]), 16, 0, 0);
    }
    __syncthreads();
#pragma unroll
    for (int ks = 0; ks < 2; ++ks) {
      short8 af[2], bf[4];
#pragma unroll
      for (int i = 0; i < 2; ++i)
        af[i] = *(const short8*)&lds[((wr * 2 + i) * 2 + ks) * 512 + lane * 8];
#pragma unroll
      for (int j = 0; j < 4; ++j)
        bf[j] = *(const short8*)&lds[(8 + (wc * 4 + j) * 2 + ks) * 512 + lane * 8];
#pragma unroll
      for (int i = 0; i < 2; ++i)
#pragma unroll
        for (int j = 0; j < 4; ++j) acc[i][j] = mfma16(af[i], bf[j], acc[i][j]);
    }
    __syncthreads();
  }
  const int r0 = (lane >> 4) * 4;
#pragma unroll
  for (int i = 0; i < 2; ++i)
#pragma unroll
    for (int j = 0; j < 4; ++j)
#pragma unroll
      for (int r = 0; r < 4; ++r) {
        int row = tm + (wr * 2 + i) * 16 + r0 + r;
        int col = tn + (wc * 4 + j) * 16 + lrow;
        C[(size_t)row * N + col] = acc[i][j][r];
      }
}

// ---------------------------------------------------------------------------
// Flash attention: fixed-offset softmax, fully unrolled, SINGLE-buffered K
// (LDS 50 KB -> 3 WG/CU, up from 2 with dbuf; dbuf measured only ~3 us while
// costing an occupancy step). V prefetched to registers (no LDS cost).
// K-staging drain per block is L2-latency thanks to XCD head pinning
// (2 heads/XCD -> K+V 2 MB < 4 MB L2); 12 waves/CU cover it.
// ---------------------------------------------------------------------------
__global__ __launch_bounds__(256) void attn_kernel(const unsigned short* __restrict__ qkv,
                                                   unsigned short* __restrict__ aout) {
  __shared__ unsigned short Klds[16 * 512];   // 16 KB A-frag chunks (kt,ks)
  __shared__ unsigned short VT[64 * 136];     // V^T [d][key], stride 136
  __shared__ unsigned short PT[4][16 * 136];  // per-wave P^T [q][key]

  const int tid = threadIdx.x;
  const int lane = tid & 63;
  const int w = tid >> 6;
  const int lrow = lane & 15;
  const int lkg = lane >> 4;

  const int i = blockIdx.x;
  const int half = i >> 8;
  const int j = (i >> 3) & 31;
  const int h = 2 * (i & 7) + half;
  const int qb = half ? (31 - j) : j;
  const int q0 = qb * 128;

  short8 qf[2][2];
#pragma unroll
  for (int qt = 0; qt < 2; ++qt)
#pragma unroll
    for (int ks = 0; ks < 2; ++ks)
      qf[qt][ks] = *(const short8*)&qkv[(size_t)(q0 + qt * 64 + w * 16 + lrow) * 3072 +
                                        h * 64 + ks * 32 + lkg * 8];

  float l_i[2] = {0.f, 0.f};
  floatx4 o[4][2];
#pragma unroll
  for (int qt = 0; qt < 2; ++qt)
#pragma unroll
    for (int nt = 0; nt < 4; ++nt) o[nt][qt] = floatx4{0.f, 0.f, 0.f, 0.f};

  const float scale2 = 0.125f * 1.44269504088896f;  // 1/sqrt(64) * log2(e)
  const float OFF = 16.0f;                          // fixed softmax offset (log2)

  // ---- prologue: stage sink K (chunks 0,1) + sink V^T; prefetch V(kb0) ----
  if (w < 2) {
    const unsigned short* g = &qkv[(size_t)lrow * 3072 + 1024 + h * 64 + w * 32 + lkg * 8];
    __builtin_amdgcn_global_load_lds((const AS1 uint32_t*)g,
                                     (AS3 uint32_t*)(&Klds[w * 512]), 16, 0, 0);
  }
  if (lane < 16) {  // sink V^T keys 0..31 (PV spans 0..31; P=0 for 16..31)
    const unsigned short* g0 = &qkv[(size_t)(2 * lane) * 3072 + 2048 + h * 64 + w * 16];
    ushort8 a0 = *(const ushort8*)g0;
    ushort8 a1 = *(const ushort8*)(g0 + 8);
    ushort8 b0 = *(const ushort8*)(g0 + 3072);
    ushort8 b1 = *(const ushort8*)(g0 + 3080);
    uint32_t* vt = (uint32_t*)VT;
#pragma unroll
    for (int dd = 0; dd < 8; ++dd) {
      vt[(w * 16 + dd) * 68 + lane] = (uint32_t)a0[dd] | ((uint32_t)b0[dd] << 16);
      vt[(w * 16 + 8 + dd) * 68 + lane] = (uint32_t)a1[dd] | ((uint32_t)b1[dd] << 16);
    }
  }
  const int kb0 = (q0 - 511 < 16) ? 16 : (q0 - 511);
  ushort8 va0, va1, vb0, vb1;  // V register prefetch for the next window block
  {
    const unsigned short* g0 = &qkv[(size_t)(kb0 + 2 * lane) * 3072 + 2048 + h * 64 + w * 16];
    va0 = *(const ushort8*)g0;
    va1 = *(const ushort8*)(g0 + 8);
    vb0 = *(const ushort8*)(g0 + 3072);
    vb1 = *(const ushort8*)(g0 + 3080);
  }
  __syncthreads();

  // ---- sink compute (keys 0..15; PV over 0..31 with P=0 padding) ----
#pragma unroll
  for (int qt = 0; qt < 2; ++qt) {
    const int qq = q0 + qt * 64 + w * 16 + lrow;
    floatx4 s0 = floatx4{0.f, 0.f, 0.f, 0.f};
#pragma unroll
    for (int ks = 0; ks < 2; ++ks) {
      short8 kf = *(const short8*)&Klds[ks * 512 + lane * 8];
      s0 = mfma16(kf, qf[qt][ks], s0);
    }
    float p[4];
#pragma unroll
    for (int r = 0; r < 4; ++r) {
      int key = lkg * 4 + r;
      bool vis = (key <= qq) && ((key < 4) || (key >= qq - 511));
      float sv = vis ? fmaf(s0[r], scale2, -OFF) : -1e30f;
      p[r] = exp2f(sv);
    }
    l_i[qt] += (p[0] + p[1]) + (p[2] + p[3]);
    *(uint2*)&PT[w][lrow * 136 + lkg * 4] =
        uint2{cvt_pk_bf16(p[0], p[1]), cvt_pk_bf16(p[2], p[3])};
    *(uint2*)&PT[w][lrow * 136 + 16 + lkg * 4] = uint2{0u, 0u};
    short8 pf = *(const short8*)&PT[w][lrow * 136 + lkg * 8];
#pragma unroll
    for (int nt = 0; nt < 4; ++nt) {
      short8 vf = *(const short8*)&VT[(nt * 16 + lrow) * 136 + lkg * 8];
      o[nt][qt] = mfma16(vf, pf, o[nt][qt]);
    }
  }

  // ---- window blocks of 128 keys (single-buffered K) ----
  for (int kb = kb0; kb < q0 + 128; kb += 128) {
    const bool hasnext = (kb + 128 < q0 + 128);
    __syncthreads();  // all waves done reading Klds/VT of previous phase
    // stage K(kb): wave w -> chunks 4w..4w+3
#pragma unroll
    for (int c = 0; c < 4; ++c) {
      int ch = w * 4 + c;
      int kt = ch >> 1, ks = ch & 1;
      const unsigned short* g =
          &qkv[(size_t)(kb + kt * 16 + lrow) * 3072 + 1024 + h * 64 + ks * 32 + lkg * 8];
      __builtin_amdgcn_global_load_lds((const AS1 uint32_t*)g,
                                       (AS3 uint32_t*)(&Klds[ch * 512]), 16, 0, 0);
    }
    {  // write V^T(kb) from prefetched registers
      uint32_t* vt = (uint32_t*)VT;
#pragma unroll
      for (int dd = 0; dd < 8; ++dd) {
        vt[(w * 16 + dd) * 68 + lane] = (uint32_t)va0[dd] | ((uint32_t)vb0[dd] << 16);
        vt[(w * 16 + 8 + dd) * 68 + lane] = (uint32_t)va1[dd] | ((uint32_t)vb1[dd] << 16);
      }
    }
    __syncthreads();  // K landed (vmcnt drain), VT visible

    if (hasnext) {  // prefetch V(kb+128) into registers during compute
      const unsigned short* g0 =
          &qkv[(size_t)(kb + 128 + 2 * lane) * 3072 + 2048 + h * 64 + w * 16];
      va0 = *(const ushort8*)g0;
      va1 = *(const ushort8*)(g0 + 8);
      vb0 = *(const ushort8*)(g0 + 3072);
      vb1 = *(const ushort8*)(g0 + 3080);
    }

#pragma unroll
    for (int qt = 0; qt < 2; ++qt) {
      const int qaT = q0 + qt * 64 + w * 16;  // wave-uniform
      const int qq = qaT + lrow;
      floatx4 s[8];
#pragma unroll
      for (int ct = 0; ct < 8; ++ct) {
        s[ct] = floatx4{0.f, 0.f, 0.f, 0.f};
#pragma unroll
        for (int ks = 0; ks < 2; ++ks) {
          short8 kf = *(const short8*)&Klds[(ct * 2 + ks) * 512 + lane * 8];
          s[ct] = mfma16(kf, qf[qt][ks], s[ct]);
        }
      }
      const bool full = (kb + 127 <= qaT) && (kb >= qaT + 15 - 511);
      float ps = 0.f;
#pragma unroll
      for (int ct = 0; ct < 8; ++ct) {
        float p[4];
#pragma unroll
        for (int r = 0; r < 4; ++r) {
          float sv = fmaf(s[ct][r], scale2, -OFF);
          if (!full) {
            int key = kb + ct * 16 + lkg * 4 + r;
            bool vis = (key <= qq) && (key >= qq - 511);
            sv = vis ? sv : -1e30f;
          }
          p[r] = exp2f(sv);
        }
        ps += (p[0] + p[1]) + (p[2] + p[3]);
        *(uint2*)&PT[w][lrow * 136 + ct * 16 + lkg * 4] =
            uint2{cvt_pk_bf16(p[0], p[1]), cvt_pk_bf16(p[2], p[3])};
      }
      l_i[qt] += ps;

#pragma unroll
      for (int kk = 0; kk < 4; ++kk) {
        short8 pf = *(const short8*)&PT[w][lrow * 136 + kk * 32 + lkg * 8];
#pragma unroll
        for (int nt = 0; nt < 4; ++nt) {
          short8 vf = *(const short8*)&VT[(nt * 16 + lrow) * 136 + kk * 32 + lkg * 8];
          o[nt][qt] = mfma16(vf, pf, o[nt][qt]);
        }
      }
    }
  }

  // single final l reduction across the 4 key-stripes (lanes share lrow=q)
#pragma unroll
  for (int qt = 0; qt < 2; ++qt) {
    float l = l_i[qt];
    l += __shfl_xor(l, 16);
    l += __shfl_xor(l, 32);
    const float inv = 1.0f / l;
    const int qq = q0 + qt * 64 + w * 16 + lrow;
#pragma unroll
    for (int nt = 0; nt < 4; ++nt) {
      floatx4 ov = o[nt][qt];
      uint32_t lo = cvt_pk_bf16(ov[0] * inv, ov[1] * inv);
      uint32_t hi = cvt_pk_bf16(ov[2] * inv, ov[3] * inv);
      *(uint2*)&aout[(size_t)qq * 1024 + h * 64 + nt * 16 + lkg * 4] = uint2{lo, hi};
    }
  }
}

// ---------------------------------------------------------------------------
extern "C" void kernel_launch(void* const* d_in, const int* in_sizes, int n_in,
                              void* d_out, int out_size, void* d_ws, size_t ws_size,
                              hipStream_t stream) {
  const float* x = (const float*)d_in[0];
  const float* wq = (const float*)d_in[1];
  const float* wk = (const float*)d_in[2];
  const float* wv = (const float*)d_in[3];
  const float* wo = (const float*)d_in[4];

  char* ws = (char*)d_ws;
  unsigned short* Xb = (unsigned short*)(ws);                 // 8 MB
  unsigned short* Wqkv = (unsigned short*)(ws + (8u << 20));  // 6 MB
  unsigned short* Wob = (unsigned short*)(ws + (14u << 20));  // 2 MB
  unsigned short* QKV = (unsigned short*)(ws + (16u << 20));  // 24 MB
  unsigned short* AO = (unsigned short*)(ws + (40u << 20));   // 8 MB

  convert_pack<<<8192, 256, 0, stream>>>((const float4*)x, (const float4*)wq,
                                         (const float4*)wk, (const float4*)wv,
                                         (const float4*)wo, (ushort4*)Xb,
                                         (ushort4*)Wqkv, (ushort4*)Wob);
  gemm_bt<unsigned short><<<dim3(32, 24), 256, 0, stream>>>(Xb, Wqkv, QKV, 3072, 1024);
  attn_kernel<<<512, 256, 0, stream>>>(QKV, AO);
  gemm64<<<dim3(64, 8), 256, 0, stream>>>(AO, Wob, (float*)d_out, 1024, 1024);
}